// Round 2
// baseline (824.042 us; speedup 1.0000x reference)
//
#include <hip/hip_runtime.h>
#include <hip/hip_bf16.h>

#define EMBED 256
#define HEADS 8
#define LEVELS 4
#define POINTS 4
#define HEAD_DIM 32
#define HPAD 128
#define WPAD 128
#define LN_EPS 1e-5f

typedef __hip_bfloat16 bf16;

static __device__ __forceinline__ float bu2f(unsigned short u) {
  return __uint_as_float(((unsigned)u) << 16);
}
// dtype codes: 0 = fp32 fixed, 1 = bf16 fixed, 2 = use runtime flag
static __device__ __forceinline__ float loadf(const void* p, size_t i, int isbf) {
  return isbf ? __bfloat162float(((const bf16*)p)[i]) : ((const float*)p)[i];
}
static __device__ __forceinline__ float4 load4(const void* p, size_t i, int isbf) {
  if (isbf) {
    ushort4 v = *reinterpret_cast<const ushort4*>((const bf16*)p + i);
    return make_float4(bu2f(v.x), bu2f(v.y), bu2f(v.z), bu2f(v.w));
  }
  return *reinterpret_cast<const float4*>((const float*)p + i);
}

// ------------- dtype probe: low-16-bit exponent plausibility on N(0,1) data -------------
__global__ __launch_bounds__(256) void detect_kernel(const unsigned* __restrict__ q,
                                                     int* __restrict__ flag) {
  int t = threadIdx.x;
  __shared__ int s[256];
  unsigned u = q[t * 13 + 1];           // scattered samples, well within buffer either way
  unsigned e = (u >> 7) & 0xFF;         // exponent field of low-16 bits viewed as bf16
  s[t] = (e >= 116 && e <= 130) ? 1 : 0;
  __syncthreads();
  for (int st = 128; st > 0; st >>= 1) { if (t < st) s[t] += s[t + st]; __syncthreads(); }
  if (t == 0) *flag = (s[0] > 200) ? 1 : 0;   // 1 => buffer holds bf16 elements
}

// ---------------- LayerNorm: one block (256 threads) per query row ----------------
__global__ __launch_bounds__(256) void ln_kernel(const void* __restrict__ q,
                                                 const void* __restrict__ g,
                                                 const void* __restrict__ be,
                                                 float* __restrict__ out,
                                                 const int* __restrict__ dflag) {
  int fl = *dflag;
  int row = blockIdx.x;
  int t = threadIdx.x;
  __shared__ float sh[256];
  float v = loadf(q, (size_t)row * EMBED + t, fl);
  sh[t] = v;
  __syncthreads();
  for (int s = 128; s > 0; s >>= 1) { if (t < s) sh[t] += sh[t + s]; __syncthreads(); }
  float mu = sh[0] * (1.f / 256.f);
  __syncthreads();
  float xc = v - mu;
  sh[t] = xc * xc;
  __syncthreads();
  for (int s = 128; s > 0; s >>= 1) { if (t < s) sh[t] += sh[t + s]; __syncthreads(); }
  float r = rsqrtf(sh[0] * (1.f / 256.f) + LN_EPS);
  out[(size_t)row * EMBED + t] = xc * r * loadf(g, t, fl) + loadf(be, t, fl);
}

// ---------------- Generic tiled GEMM: C[M,N] = A[M,K]@B[K,N] (+bias) (+resid) ------
// OUTMODE: 0 = fp32, 1 = bf16, 2 = flag dtype
template <int OUTMODE>
__global__ __launch_bounds__(256) void gemm_kernel(const void* __restrict__ A, int Ac,
                                                   const void* __restrict__ B, int Bc,
                                                   const void* __restrict__ bias,
                                                   const void* __restrict__ resid, int Rc,
                                                   void* __restrict__ Cv,
                                                   int M, int N, int K,
                                                   const int* __restrict__ dflag) {
  int fl = *dflag;
  int abf = (Ac == 2) ? fl : Ac;
  int bbf = (Bc == 2) ? fl : Bc;
  int rbf = (Rc == 2) ? fl : Rc;
  int obf = (OUTMODE == 2) ? fl : OUTMODE;

  __shared__ float As[16][68];  // As[k][m]
  __shared__ float Bs[16][68];  // Bs[k][n]
  int tid = threadIdx.x;
  int tx = tid & 15, ty = tid >> 4;
  int m0 = blockIdx.x * 64, n0 = blockIdx.y * 64;

  int ar = tid >> 2;            // A tile row 0..63
  int ac = (tid & 3) * 4;       // A tile k-offset {0,4,8,12}
  int bk = tid >> 4;            // B tile k 0..15
  int bc = (tid & 15) * 4;      // B tile col

  float acc[4][4] = {};

  for (int k0 = 0; k0 < K; k0 += 16) {
    float4 av = make_float4(0.f, 0.f, 0.f, 0.f);
    int gr = m0 + ar;
    if (gr < M) av = load4(A, (size_t)gr * K + k0 + ac, abf);
    float4 bv = load4(B, (size_t)(k0 + bk) * N + n0 + bc, bbf);
    __syncthreads();
    As[ac + 0][ar] = av.x; As[ac + 1][ar] = av.y; As[ac + 2][ar] = av.z; As[ac + 3][ar] = av.w;
    Bs[bk][bc + 0] = bv.x; Bs[bk][bc + 1] = bv.y; Bs[bk][bc + 2] = bv.z; Bs[bk][bc + 3] = bv.w;
    __syncthreads();
#pragma unroll
    for (int kk = 0; kk < 16; ++kk) {
      float4 a = *reinterpret_cast<const float4*>(&As[kk][ty * 4]);
      float4 b = *reinterpret_cast<const float4*>(&Bs[kk][tx * 4]);
      acc[0][0] += a.x * b.x; acc[0][1] += a.x * b.y; acc[0][2] += a.x * b.z; acc[0][3] += a.x * b.w;
      acc[1][0] += a.y * b.x; acc[1][1] += a.y * b.y; acc[1][2] += a.y * b.z; acc[1][3] += a.y * b.w;
      acc[2][0] += a.z * b.x; acc[2][1] += a.z * b.y; acc[2][2] += a.z * b.z; acc[2][3] += a.z * b.w;
      acc[3][0] += a.w * b.x; acc[3][1] += a.w * b.y; acc[3][2] += a.w * b.z; acc[3][3] += a.w * b.w;
    }
  }

#pragma unroll
  for (int i = 0; i < 4; i++) {
    int r = m0 + ty * 4 + i;
    if (r >= M) continue;
#pragma unroll
    for (int j = 0; j < 4; j++) {
      int c = n0 + tx * 4 + j;
      float v = acc[i][j];
      if (bias)  v += loadf(bias, c, bbf);
      if (resid) v += loadf(resid, (size_t)r * N + c, rbf);
      if (obf) ((bf16*)Cv)[(size_t)r * N + c] = __float2bfloat16(v);
      else     ((float*)Cv)[(size_t)r * N + c] = v;
    }
  }
}

// ---------------- Deformable sampling: one block per query, t = h*32 + d ----------------
__global__ __launch_bounds__(256) void sample_kernel(const float* __restrict__ off,
                                                     const float* __restrict__ attnlog,
                                                     const void* __restrict__ qsp,
                                                     const int* __restrict__ qbo, int nb,
                                                     const int* __restrict__ lss,
                                                     const bf16* __restrict__ value,
                                                     float* __restrict__ samp,
                                                     const int* __restrict__ dflag) {
  int fl = *dflag;
  int q = blockIdx.x;
  int t = threadIdx.x;
  __shared__ float Loff[256];
  __shared__ float Lw[128];
  __shared__ float Lsh[LEVELS][2];
  __shared__ int Lb;

  Loff[t] = off[(size_t)q * 256 + t];
  if (t < 128) Lw[t] = attnlog[(size_t)q * 128 + t];
  if (t < 2 * LEVELS) Lsh[t >> 1][t & 1] = (float)lss[t];
  if (t == 0) {
    int b = 0;
    for (int i = 1; i < nb; i++)
      if (q >= qbo[i]) b = i;
    Lb = b;
  }
  __syncthreads();

  if (t < HEADS) {  // softmax over 16 (L*P) per head
    float mx = -1e30f;
    for (int i = 0; i < 16; i++) mx = fmaxf(mx, Lw[t * 16 + i]);
    float s = 0.f;
    for (int i = 0; i < 16; i++) { float e = __expf(Lw[t * 16 + i] - mx); Lw[t * 16 + i] = e; s += e; }
    float inv = 1.f / s;
    for (int i = 0; i < 16; i++) Lw[t * 16 + i] *= inv;
  }
  __syncthreads();

  int h = t >> 5, d = t & 31;
  float qy = loadf(qsp, (size_t)q * 2 + 0, fl);
  float qx = loadf(qsp, (size_t)q * 2 + 1, fl);
  const bf16* vb = value + (size_t)Lb * ((size_t)HPAD * WPAD * LEVELS * EMBED);

  float acc = 0.f;
#pragma unroll
  for (int l = 0; l < LEVELS; l++) {
    float Hl = Lsh[l][0], Wl = Lsh[l][1];
    int Hi = (int)Hl, Wi = (int)Wl;
#pragma unroll
    for (int p = 0; p < POINTS; p++) {
      int oidx = ((h * LEVELS + l) * POINTS + p) * 2;
      float a = Lw[h * 16 + l * POINTS + p];
      // match reference arithmetic order: loc = pos + off/shp; pix = loc*shp - 0.5
      float py = (qy + Loff[oidx + 0] / Hl) * Hl - 0.5f;
      float px = (qx + Loff[oidx + 1] / Wl) * Wl - 0.5f;
      float y0f = floorf(py), x0f = floorf(px);
      float wy = py - y0f, wx = px - x0f;
      int y0 = (int)y0f, x0 = (int)x0f;
#pragma unroll
      for (int cy = 0; cy < 2; cy++) {
#pragma unroll
        for (int cx = 0; cx < 2; cx++) {
          int yi = y0 + cy, xi = x0 + cx;
          float w = (cy ? wy : 1.f - wy) * (cx ? wx : 1.f - wx);
          if (yi >= 0 && yi < Hi && xi >= 0 && xi < Wi && w != 0.f) {
            float v = __bfloat162float(vb[(((size_t)yi * WPAD + xi) * LEVELS + l) * EMBED + h * HEAD_DIM + d]);
            acc += a * w * v;
          }
        }
      }
    }
  }
  samp[(size_t)q * 256 + t] = acc;
}

extern "C" void kernel_launch(void* const* d_in, const int* in_sizes, int n_in,
                              void* d_out, int out_size, void* d_ws, size_t ws_size,
                              hipStream_t stream) {
  const void* query  = d_in[0];
  const void* qsp    = d_in[1];
  const int*  qbo    = (const int*)d_in[2];
  const void* sfm    = d_in[3];
  const int*  lss    = (const int*)d_in[4];
  const void* gamma  = d_in[5];
  const void* beta   = d_in[6];
  const void* W_q    = d_in[7];
  const void* W_off  = d_in[8];
  const void* b_off  = d_in[9];
  const void* W_attn = d_in[10];
  const void* b_attn = d_in[11];
  const void* W_val  = d_in[12];
  const void* b_val  = d_in[13];
  const void* W_out  = d_in[14];

  const int Q  = in_sizes[0] / EMBED;      // 20000
  const int nb = in_sizes[2] - 1;          // 2
  const int MV = in_sizes[3] / EMBED;      // B*HP*WP*LEVELS = 131072

  char* ws = (char*)d_ws;
  size_t o = 0;
  auto alloc = [&](size_t bytes) { size_t r = o; o = (o + bytes + 255) & ~(size_t)255; return r; };
  float* xln   = (float*)(ws + alloc((size_t)Q * EMBED * sizeof(float)));
  float* x     = (float*)(ws + alloc((size_t)Q * EMBED * sizeof(float)));
  float* offw  = (float*)(ws + alloc((size_t)Q * 256 * sizeof(float)));
  float* attnw = (float*)(ws + alloc((size_t)Q * 128 * sizeof(float)));
  bf16*  valw  = (bf16*)(ws + alloc((size_t)MV * EMBED * sizeof(bf16)));
  float* sampw = (float*)(ws + alloc((size_t)Q * EMBED * sizeof(float)));
  int*   dflag = (int*)(ws + alloc(256));
  (void)ws_size;

  // 0) dtype probe on query (N(0,1) data)
  detect_kernel<<<1, 256, 0, stream>>>((const unsigned*)query, dflag);

  // 1) LayerNorm -> fp32
  ln_kernel<<<Q, 256, 0, stream>>>(query, gamma, beta, xln, dflag);

  // 2) x = xln @ W_q   (fp32 out)
  dim3 gq((Q + 63) / 64, EMBED / 64);
  gemm_kernel<0><<<gq, 256, 0, stream>>>(xln, 0, W_q, 2, nullptr, nullptr, 0, x, Q, EMBED, EMBED, dflag);

  // 3) off = x @ W_off + b_off  (fp32 out)
  gemm_kernel<0><<<gq, 256, 0, stream>>>(x, 0, W_off, 2, b_off, nullptr, 0, offw, Q, 256, EMBED, dflag);

  // 4) attn logits = x @ W_attn + b_attn  (fp32 out)
  dim3 ga((Q + 63) / 64, 128 / 64);
  gemm_kernel<0><<<ga, 256, 0, stream>>>(x, 0, W_attn, 2, b_attn, nullptr, 0, attnw, Q, 128, EMBED, dflag);

  // 5) value = sfm @ W_val + b_val  (bf16 out)
  dim3 gv((MV + 63) / 64, EMBED / 64);
  gemm_kernel<1><<<gv, 256, 0, stream>>>(sfm, 2, W_val, 2, b_val, nullptr, 0, valw, MV, EMBED, EMBED, dflag);

  // 6) deformable bilinear sampling + attention-weighted sum  (fp32 out)
  sample_kernel<<<Q, 256, 0, stream>>>(offw, attnw, qsp, qbo, nb, lss, valw, sampw, dflag);

  // 7) out = sampw @ W_out + residual(query)   (output dtype = input dtype)
  gemm_kernel<2><<<gq, 256, 0, stream>>>(sampw, 0, W_out, 2, nullptr, query, 2, d_out, Q, EMBED, EMBED, dflag);
}

// Round 3
// 481.245 us; speedup vs baseline: 1.7123x; 1.7123x over previous
//
#include <hip/hip_runtime.h>
#include <hip/hip_bf16.h>
#include <stdint.h>

#define EMBED 256
#define HEADS 8
#define LEVELS 4
#define POINTS 4
#define HEAD_DIM 32
#define HPAD 128
#define WPAD 128
#define LN_EPS 1e-5f

typedef unsigned short u16;
typedef __attribute__((ext_vector_type(8))) short bf16x8v;   // 8 bf16 in 4 VGPRs
typedef __attribute__((ext_vector_type(4))) float f32x4;

static __device__ __forceinline__ float bu2f(u16 u) {
  return __uint_as_float(((unsigned)u) << 16);
}
static __device__ __forceinline__ u16 f2bu(float f) {   // fp32 -> bf16 RNE
  unsigned x = __float_as_uint(f);
  return (u16)((x + 0x7fffu + ((x >> 16) & 1u)) >> 16);
}
// flag-aware scalar load: isbf ? bf16 : fp32
static __device__ __forceinline__ float loadf(const void* p, size_t i, int isbf) {
  return isbf ? bu2f(((const u16*)p)[i]) : ((const float*)p)[i];
}
static __device__ __forceinline__ int imin(int a, int b) { return a < b ? a : b; }

// 16-byte global -> LDS async copy
static __device__ __forceinline__ void cp16(const u16* g, u16* l) {
  __builtin_amdgcn_global_load_lds((const __attribute__((address_space(1))) unsigned*)g,
                                   (__attribute__((address_space(3))) unsigned*)l, 16, 0, 0);
}

// ------------- dtype probe: low-16-bit exponent plausibility on N(0,1) data -------------
__global__ __launch_bounds__(256) void detect_kernel(const unsigned* __restrict__ q,
                                                     int* __restrict__ flag) {
  int t = threadIdx.x;
  __shared__ int s[256];
  unsigned u = q[t * 13 + 1];
  unsigned e = (u >> 7) & 0xFF;         // exponent of low-16 viewed as bf16
  s[t] = (e >= 116 && e <= 130) ? 1 : 0;
  __syncthreads();
  for (int st = 128; st > 0; st >>= 1) { if (t < st) s[t] += s[t + st]; __syncthreads(); }
  if (t == 0) *flag = (s[0] > 200) ? 1 : 0;   // 1 => bf16 elements
}

// ------------- weight transpose+convert: Wt[n*K+k] = bf16(W[k*N+n]) -------------
__global__ __launch_bounds__(256) void wtrans_kernel(const void* __restrict__ W,
                                                     u16* __restrict__ Wt,
                                                     int K, int N,
                                                     const int* __restrict__ dflag) {
  int fl = *dflag;
  int i = blockIdx.x * 256 + threadIdx.x;
  if (i >= N * K) return;
  int n = i / K, k = i - n * K;
  Wt[i] = f2bu(loadf(W, (size_t)k * N + n, fl));
}

// ---------------- LayerNorm: one block per query row, bf16 out ----------------
__global__ __launch_bounds__(256) void ln_kernel(const void* __restrict__ q,
                                                 const void* __restrict__ g,
                                                 const void* __restrict__ be,
                                                 u16* __restrict__ out,
                                                 const int* __restrict__ dflag) {
  int fl = *dflag;
  int row = blockIdx.x;
  int t = threadIdx.x;
  __shared__ float sh[256];
  float v = loadf(q, (size_t)row * EMBED + t, fl);
  sh[t] = v;
  __syncthreads();
  for (int s = 128; s > 0; s >>= 1) { if (t < s) sh[t] += sh[t + s]; __syncthreads(); }
  float mu = sh[0] * (1.f / 256.f);
  __syncthreads();
  float xc = v - mu;
  sh[t] = xc * xc;
  __syncthreads();
  for (int s = 128; s > 0; s >>= 1) { if (t < s) sh[t] += sh[t + s]; __syncthreads(); }
  float r = rsqrtf(sh[0] * (1.f / 256.f) + LN_EPS);
  out[(size_t)row * EMBED + t] = f2bu(xc * r * loadf(g, t, fl) + loadf(be, t, fl));
}

// ---------------- MFMA GEMM: C[M,N] = A[M,K] @ Bt[N,K]^T (+bias)(+resid) ----------------
// 128x128 tile, 256 threads (4 waves, 2x2 of 64x64), BK=32, 16x16x32 bf16 MFMA.
// ABF: A is bf16 (global_load_lds staging). !ABF: A is flag-dtype (VGPR convert staging).
// OUTMODE: 0 fp32, 1 bf16, 2 flag dtype. bias/resid are flag dtype.
template <int OUTMODE, bool ABF>
__global__ __launch_bounds__(256) void mfma_gemm(const void* __restrict__ A,
                                                 const u16* __restrict__ Bt,
                                                 const void* __restrict__ bias,
                                                 const void* __restrict__ resid,
                                                 void* __restrict__ Cv,
                                                 int M, int N, int K,
                                                 const int* __restrict__ dflag) {
  int fl = *dflag;
  __shared__ u16 As[128 * 32];
  __shared__ u16 Bs[128 * 32];
  int tid = threadIdx.x;
  int m0 = blockIdx.x * 128, n0 = blockIdx.y * 128;
  int wave = tid >> 6, lane = tid & 63;
  int quad = lane >> 4, r16 = lane & 15;
  int wm = (wave >> 1) * 64, wn = (wave & 1) * 64;

  f32x4 acc[4][4];
#pragma unroll
  for (int i = 0; i < 4; i++)
#pragma unroll
    for (int j = 0; j < 4; j++) acc[i][j] = (f32x4){0.f, 0.f, 0.f, 0.f};

  // staging pieces: 512 x 16B per tile; thread does pieces tid and tid+256
  int p0 = tid, p1 = tid + 256;
  int r0 = p0 >> 2, c0 = (p0 & 3) * 8;
  int r1 = p1 >> 2, c1 = (p1 & 3) * 8;
  int ra0 = imin(m0 + r0, M - 1), ra1 = imin(m0 + r1, M - 1);

  for (int k0 = 0; k0 < K; k0 += 32) {
    __syncthreads();   // previous iteration's LDS reads complete
    if (ABF) {
      const u16* Ab = (const u16*)A;
      cp16(Ab + (size_t)ra0 * K + k0 + c0, &As[p0 * 8]);
      cp16(Ab + (size_t)ra1 * K + k0 + c1, &As[p1 * 8]);
    } else if (fl) {
      const u16* Ab = (const u16*)A;
      int4 v0 = *(const int4*)(Ab + (size_t)ra0 * K + k0 + c0);
      int4 v1 = *(const int4*)(Ab + (size_t)ra1 * K + k0 + c1);
      *(int4*)&As[p0 * 8] = v0;
      *(int4*)&As[p1 * 8] = v1;
    } else {
      const float* Af = (const float*)A;
      float4 f00 = *(const float4*)(Af + (size_t)ra0 * K + k0 + c0);
      float4 f01 = *(const float4*)(Af + (size_t)ra0 * K + k0 + c0 + 4);
      float4 f10 = *(const float4*)(Af + (size_t)ra1 * K + k0 + c1);
      float4 f11 = *(const float4*)(Af + (size_t)ra1 * K + k0 + c1 + 4);
      u16* d0 = &As[p0 * 8];
      d0[0] = f2bu(f00.x); d0[1] = f2bu(f00.y); d0[2] = f2bu(f00.z); d0[3] = f2bu(f00.w);
      d0[4] = f2bu(f01.x); d0[5] = f2bu(f01.y); d0[6] = f2bu(f01.z); d0[7] = f2bu(f01.w);
      u16* d1 = &As[p1 * 8];
      d1[0] = f2bu(f10.x); d1[1] = f2bu(f10.y); d1[2] = f2bu(f10.z); d1[3] = f2bu(f10.w);
      d1[4] = f2bu(f11.x); d1[5] = f2bu(f11.y); d1[6] = f2bu(f11.z); d1[7] = f2bu(f11.w);
    }
    cp16(Bt + (size_t)(n0 + r0) * K + k0 + c0, &Bs[p0 * 8]);
    cp16(Bt + (size_t)(n0 + r1) * K + k0 + c1, &Bs[p1 * 8]);
    __syncthreads();   // compiler drains vmcnt/lgkm before barrier

    bf16x8v a[4], b[4];
#pragma unroll
    for (int i = 0; i < 4; i++)
      a[i] = *(const bf16x8v*)&As[(wm + i * 16 + r16) * 32 + quad * 8];
#pragma unroll
    for (int j = 0; j < 4; j++)
      b[j] = *(const bf16x8v*)&Bs[(wn + j * 16 + r16) * 32 + quad * 8];
#pragma unroll
    for (int i = 0; i < 4; i++)
#pragma unroll
      for (int j = 0; j < 4; j++)
        acc[i][j] = __builtin_amdgcn_mfma_f32_16x16x32_bf16(a[i], b[j], acc[i][j], 0, 0, 0);
  }

  int obf = (OUTMODE == 2) ? fl : OUTMODE;
#pragma unroll
  for (int j = 0; j < 4; j++) {
    int col = n0 + wn + j * 16 + r16;
    float bv = bias ? loadf(bias, col, fl) : 0.f;
#pragma unroll
    for (int i = 0; i < 4; i++) {
#pragma unroll
      for (int reg = 0; reg < 4; reg++) {
        int row = m0 + wm + i * 16 + quad * 4 + reg;
        if (row < M) {
          float v = acc[i][j][reg] + bv;
          if (resid) v += loadf(resid, (size_t)row * N + col, fl);
          if (obf) ((u16*)Cv)[(size_t)row * N + col] = f2bu(v);
          else     ((float*)Cv)[(size_t)row * N + col] = v;
        }
      }
    }
  }
}

// ---------------- Deformable sampling v2: 2 queries/block ----------------
// phase 1: 128 threads/query compute (h,l,p) tuples -> corner offsets+weights in LDS
// phase 2: 128 threads/query (h, d-pair) gather bf16x2 and accumulate
__global__ __launch_bounds__(256) void sample2_kernel(const float* __restrict__ off,
                                                      const float* __restrict__ attnlog,
                                                      const void* __restrict__ qsp,
                                                      const int* __restrict__ qbo, int nb,
                                                      const int* __restrict__ lss,
                                                      const u16* __restrict__ value,
                                                      u16* __restrict__ samp, int Qn,
                                                      const int* __restrict__ dflag) {
  int fl = *dflag;
  int t = threadIdx.x;
  int q2 = t >> 7;
  int i7 = t & 127;
  int qb = blockIdx.x * 2;
  int q = imin(qb + q2, Qn - 1);

  __shared__ float Loff[2][256];
  __shared__ float Lw[2][128];
  __shared__ int   Lb[2];
  __shared__ int   Co[2][128][4];
  __shared__ float Cw[2][128][4];

  {
    float2 v = ((const float2*)(off + (size_t)q * 256))[i7];
    Loff[q2][i7 * 2]     = v.x;
    Loff[q2][i7 * 2 + 1] = v.y;
    Lw[q2][i7] = attnlog[(size_t)q * 128 + i7];
  }
  if (t < 2) {
    int qq = imin(qb + t, Qn - 1);
    int b = 0;
    for (int i = 1; i < nb; i++) if (qq >= qbo[i]) b = i;
    Lb[t] = b;
  }
  __syncthreads();

  if (t < 16) {  // softmax over 16 (l,p) per (q2,h)
    int sq = t >> 3, h = t & 7;
    float* w = &Lw[sq][h * 16];
    float mx = w[0];
    for (int i = 1; i < 16; i++) mx = fmaxf(mx, w[i]);
    float s = 0.f;
    for (int i = 0; i < 16; i++) { float e = __expf(w[i] - mx); w[i] = e; s += e; }
    float inv = 1.f / s;
    for (int i = 0; i < 16; i++) w[i] *= inv;
  }
  __syncthreads();

  {  // tuple phase: one (q2,h,l,p) per thread
    int h = i7 >> 4, lp = i7 & 15, l = lp >> 2;
    int Hi = lss[l * 2], Wi = lss[l * 2 + 1];
    float Hl = (float)Hi, Wl = (float)Wi;
    float qy = loadf(qsp, (size_t)q * 2, fl);
    float qx = loadf(qsp, (size_t)q * 2 + 1, fl);
    float a  = Lw[q2][i7];
    float oy = Loff[q2][i7 * 2], ox = Loff[q2][i7 * 2 + 1];
    float py = (qy + oy / Hl) * Hl - 0.5f;   // reference arithmetic order
    float px = (qx + ox / Wl) * Wl - 0.5f;
    float y0f = floorf(py), x0f = floorf(px);
    float wy = py - y0f, wx = px - x0f;
    int y0 = (int)y0f, x0 = (int)x0f;
    int bbase = Lb[q2] * (HPAD * WPAD * LEVELS * EMBED);
#pragma unroll
    for (int c = 0; c < 4; c++) {
      int yi = y0 + (c >> 1), xi = x0 + (c & 1);
      float w = ((c >> 1) ? wy : 1.f - wy) * ((c & 1) ? wx : 1.f - wx);
      bool ok = (yi >= 0) & (yi < Hi) & (xi >= 0) & (xi < Wi);
      Co[q2][i7][c] = ok ? (bbase + ((yi * WPAD + xi) * LEVELS + l) * EMBED + h * HEAD_DIM) : 0;
      Cw[q2][i7][c] = ok ? (a * w) : 0.f;
    }
  }
  __syncthreads();

  {  // gather phase: t = q2*128 + h*16 + d2
    int h = (t >> 4) & 7;
    int d2 = t & 15;
    float ax = 0.f, ay = 0.f;
#pragma unroll
    for (int lp = 0; lp < 16; lp++) {
      int4   o4 = *(const int4*)&Co[q2][h * 16 + lp][0];
      float4 w4 = *(const float4*)&Cw[q2][h * 16 + lp][0];
      unsigned v;
      v = *(const unsigned*)(value + o4.x + d2 * 2);
      ax += w4.x * __uint_as_float(v << 16); ay += w4.x * __uint_as_float(v & 0xffff0000u);
      v = *(const unsigned*)(value + o4.y + d2 * 2);
      ax += w4.y * __uint_as_float(v << 16); ay += w4.y * __uint_as_float(v & 0xffff0000u);
      v = *(const unsigned*)(value + o4.z + d2 * 2);
      ax += w4.z * __uint_as_float(v << 16); ay += w4.z * __uint_as_float(v & 0xffff0000u);
      v = *(const unsigned*)(value + o4.w + d2 * 2);
      ax += w4.w * __uint_as_float(v << 16); ay += w4.w * __uint_as_float(v & 0xffff0000u);
    }
    if (qb + q2 < Qn) {
      unsigned pk = (unsigned)f2bu(ax) | ((unsigned)f2bu(ay) << 16);
      *(unsigned*)(samp + (size_t)(qb + q2) * 256 + h * 32 + d2 * 2) = pk;
    }
  }
}

extern "C" void kernel_launch(void* const* d_in, const int* in_sizes, int n_in,
                              void* d_out, int out_size, void* d_ws, size_t ws_size,
                              hipStream_t stream) {
  const void* query  = d_in[0];
  const void* qsp    = d_in[1];
  const int*  qbo    = (const int*)d_in[2];
  const void* sfm    = d_in[3];
  const int*  lss    = (const int*)d_in[4];
  const void* gamma  = d_in[5];
  const void* beta   = d_in[6];
  const void* W_q    = d_in[7];
  const void* W_off  = d_in[8];
  const void* b_off  = d_in[9];
  const void* W_attn = d_in[10];
  const void* b_attn = d_in[11];
  const void* W_val  = d_in[12];
  const void* b_val  = d_in[13];
  const void* W_out  = d_in[14];

  const int Q  = in_sizes[0] / EMBED;      // 20000
  const int nb = in_sizes[2] - 1;          // 2
  const int MV = in_sizes[3] / EMBED;      // 131072

  char* ws = (char*)d_ws;
  size_t o = 0;
  auto alloc = [&](size_t bytes) { size_t r = o; o = (o + bytes + 255) & ~(size_t)255; return r; };
  u16*   xln   = (u16*)(ws + alloc((size_t)Q * EMBED * sizeof(u16)));
  u16*   x     = (u16*)(ws + alloc((size_t)Q * EMBED * sizeof(u16)));
  float* offw  = (float*)(ws + alloc((size_t)Q * 256 * sizeof(float)));
  float* attnw = (float*)(ws + alloc((size_t)Q * 128 * sizeof(float)));
  u16*   valw  = (u16*)(ws + alloc((size_t)MV * EMBED * sizeof(u16)));
  u16*   sampw = (u16*)(ws + alloc((size_t)Q * EMBED * sizeof(u16)));
  u16*   wtq   = (u16*)(ws + alloc(256 * 256 * sizeof(u16)));
  u16*   wtoff = (u16*)(ws + alloc(256 * 256 * sizeof(u16)));
  u16*   wtatt = (u16*)(ws + alloc(128 * 256 * sizeof(u16)));
  u16*   wtval = (u16*)(ws + alloc(256 * 256 * sizeof(u16)));
  u16*   wtout = (u16*)(ws + alloc(256 * 256 * sizeof(u16)));
  int*   dflag = (int*)(ws + alloc(256));
  (void)ws_size;

  // 0) dtype probe
  detect_kernel<<<1, 256, 0, stream>>>((const unsigned*)query, dflag);

  // 0b) weight transpose+convert to bf16 [N][K]
  wtrans_kernel<<<(256 * 256 + 255) / 256, 256, 0, stream>>>(W_q,    wtq,   256, 256, dflag);
  wtrans_kernel<<<(256 * 256 + 255) / 256, 256, 0, stream>>>(W_off,  wtoff, 256, 256, dflag);
  wtrans_kernel<<<(128 * 256 + 255) / 256, 256, 0, stream>>>(W_attn, wtatt, 256, 128, dflag);
  wtrans_kernel<<<(256 * 256 + 255) / 256, 256, 0, stream>>>(W_val,  wtval, 256, 256, dflag);
  wtrans_kernel<<<(256 * 256 + 255) / 256, 256, 0, stream>>>(W_out,  wtout, 256, 256, dflag);

  // 1) LayerNorm -> bf16
  ln_kernel<<<Q, 256, 0, stream>>>(query, gamma, beta, xln, dflag);

  const int GQ = (Q + 127) / 128;
  // 2) x = xln @ W_q   (bf16 out)
  mfma_gemm<1, true><<<dim3(GQ, 2), 256, 0, stream>>>(xln, wtq, nullptr, nullptr, x, Q, 256, 256, dflag);
  // 3) off = x @ W_off + b_off  (fp32 out)
  mfma_gemm<0, true><<<dim3(GQ, 2), 256, 0, stream>>>(x, wtoff, b_off, nullptr, offw, Q, 256, 256, dflag);
  // 4) attn logits = x @ W_attn + b_attn  (fp32 out)
  mfma_gemm<0, true><<<dim3(GQ, 1), 256, 0, stream>>>(x, wtatt, b_attn, nullptr, attnw, Q, 128, 256, dflag);
  // 5) value = sfm @ W_val + b_val  (bf16 out; A converted in staging)
  mfma_gemm<1, false><<<dim3(MV / 128, 2), 256, 0, stream>>>(sfm, wtval, b_val, nullptr, valw, MV, 256, 256, dflag);
  // 6) sampling (bf16 out)
  sample2_kernel<<<(Q + 1) / 2, 256, 0, stream>>>(offw, attnw, qsp, qbo, nb, lss, valw, sampw, Q, dflag);
  // 7) out = sampw @ W_out + residual(query)  (flag dtype out)
  mfma_gemm<2, true><<<dim3(GQ, 2), 256, 0, stream>>>(sampw, wtout, nullptr, query, d_out, Q, 256, 256, dflag);
}